// Round 1
// baseline (173.742 us; speedup 1.0000x reference)
//
#include <hip/hip_runtime.h>
#include <math.h>

// GeometricEmbedding: B=4, N=M=3000, d_model=2, sigma_d=1.0
// out[0..12000)  float2 = p0[b,n] * (sum_m sin d, sum_m cos d)
// out[12000..24000)     = p1[b,m] * (sum_n sin d, sum_n cos d)
// d = sqrt(max(2 - 2*<p0,p1>, 0)), sin/cos via HW trans ops (revolutions:
// fold 1/2pi into the sqrt argument -> r = sqrt(max(C2 - 2*K2*<p0,p1>,0))).
//
// R7: halve the transcendental work. Previous versions computed the BxNxM
// distance matrix twice (once per output side). Now each pair is evaluated
// ONCE: row sums accumulate in registers (4 independent rows/wave, proven
// ILP structure), column sums accumulate in LDS via ds_add_f32 atomics
// (cross-wave safe). Per-block partials go to workspace; a tiny second
// kernel reduces 188 col-partials / 2 row-halves and applies p0/p1.
// Trans floor: 36e6*3/64*16cyc/1024SIMD ~= 11us (was ~26us for 72e6 evals).

#define GB 4
#define GN 3000
#define RB 16                       // rows per block (4 waves x 4 rows)
#define BLKS 188                    // ceil(3000/16); last block: 2 active waves
#define HALF 1500                   // columns per block (2 halves per batch)
#define K2 0.025330295910584444f    // (1/2pi)^2
#define C2 0.050660591821168888f    // 2*(1/2pi)^2

// ws layout (float2 units):
//   [0, COLPART_F2): colpart[(b*BLKS+blk)*GN + m] = (sum sin, sum cos) of
//                    this block's 16 rows at column m (each block fills its
//                    1500-col half of the row (b,blk))
//   [COLPART_F2, +24000): rowpart[(b*GN+n)*2 + h] = row n's half-h sums
#define COLPART_F2 (GB*BLKS*GN)

__device__ __forceinline__ float sreg(float x) {   // pin wave-uniform to SGPR
    return __int_as_float(__builtin_amdgcn_readfirstlane(__float_as_int(x)));
}

__global__ __launch_bounds__(256, 4) void geo_pair_kernel(
    const float* __restrict__ p0,
    const float* __restrict__ p1,
    float2* __restrict__ ws)
{
    __shared__ float colsum[HALF * 2];          // 12 KB

    const int lane = threadIdx.x & 63;
    const int wv   = threadIdx.x >> 6;          // 0..3
    const int h    = blockIdx.x & 1;            // column half
    const int t    = blockIdx.x >> 1;           // 0..751
    const int b    = t / BLKS;                  // magic-mul
    const int blk  = t - b * BLKS;
    const int row0 = blk * RB + wv * 4;         // first of this wave's 4 rows

    for (int i = threadIdx.x; i < HALF * 2; i += 256) colsum[i] = 0.f;
    __syncthreads();

    float s0 = 0.f, c0 = 0.f, s1 = 0.f, c1 = 0.f;
    float s2 = 0.f, c2 = 0.f, s3 = 0.f, c3 = 0.f;

    if (row0 < GN) {                            // tail block: waves 2,3 idle
        const float2* __restrict__ ownp = (const float2*)p0 + b * GN + row0;
        const float2 pr0 = ownp[0];
        const float2 pr1 = ownp[1];
        const float2 pr2 = ownp[2];
        const float2 pr3 = ownp[3];

        const float mm = -2.0f * K2;
        const float ax0 = sreg(mm * pr0.x), ay0 = sreg(mm * pr0.y);
        const float ax1 = sreg(mm * pr1.x), ay1 = sreg(mm * pr1.y);
        const float ax2 = sreg(mm * pr2.x), ay2 = sreg(mm * pr2.y);
        const float ax3 = sreg(mm * pr3.x), ay3 = sreg(mm * pr3.y);
        const float c2v = C2;

        float* cb = &colsum[lane * 2];          // advances 128 floats/step

#define STEP(q) do {                                                         \
    float t0 = fmaf(ax0, (q).x, fmaf(ay0, (q).y, c2v));                      \
    float t1 = fmaf(ax1, (q).x, fmaf(ay1, (q).y, c2v));                      \
    float t2 = fmaf(ax2, (q).x, fmaf(ay2, (q).y, c2v));                      \
    float t3 = fmaf(ax3, (q).x, fmaf(ay3, (q).y, c2v));                      \
    t0 = fmaxf(t0, 0.f); t1 = fmaxf(t1, 0.f);                                \
    t2 = fmaxf(t2, 0.f); t3 = fmaxf(t3, 0.f);                                \
    float r0 = __builtin_amdgcn_sqrtf(t0);                                   \
    float r1 = __builtin_amdgcn_sqrtf(t1);                                   \
    float r2 = __builtin_amdgcn_sqrtf(t2);                                   \
    float r3 = __builtin_amdgcn_sqrtf(t3);                                   \
    float sn0 = __builtin_amdgcn_sinf(r0), cs0 = __builtin_amdgcn_cosf(r0);  \
    float sn1 = __builtin_amdgcn_sinf(r1), cs1 = __builtin_amdgcn_cosf(r1);  \
    float sn2 = __builtin_amdgcn_sinf(r2), cs2 = __builtin_amdgcn_cosf(r2);  \
    float sn3 = __builtin_amdgcn_sinf(r3), cs3 = __builtin_amdgcn_cosf(r3);  \
    s0 += sn0; c0 += cs0; s1 += sn1; c1 += cs1;                              \
    s2 += sn2; c2 += cs2; s3 += sn3; c3 += cs3;                              \
    atomicAdd(cb,     (sn0 + sn1) + (sn2 + sn3));                            \
    atomicAdd(cb + 1, (cs0 + cs1) + (cs2 + cs3));                            \
} while (0)

        const float2* __restrict__ qp = (const float2*)p1 + b * GN + h * HALF + lane;
        float2 qA = qp[0];
        #pragma unroll 1
        for (int j = 0; j < 22; ++j) {          // cols lane + {0..21}*64
            float2 qB = qp[64];
            qp += 64;
            STEP(qA);
            cb += 128;
            qA = qB;
        }
        STEP(qA);                               // col lane + 22*64 (1472 total)
        cb += 128;
        if (lane < 28) {                        // cols 1472..1499
            float2 qT = qp[64];
            STEP(qT);
        }
#undef STEP

        #pragma unroll
        for (int off = 32; off >= 1; off >>= 1) {
            s0 += __shfl_down(s0, off, 64);  c0 += __shfl_down(c0, off, 64);
            s1 += __shfl_down(s1, off, 64);  c1 += __shfl_down(c1, off, 64);
            s2 += __shfl_down(s2, off, 64);  c2 += __shfl_down(c2, off, 64);
            s3 += __shfl_down(s3, off, 64);  c3 += __shfl_down(c3, off, 64);
        }

        if (lane == 0) {
            float2* rp = ws + COLPART_F2 + ((b * GN + row0) << 1) + h;
            rp[0] = make_float2(s0, c0);
            rp[2] = make_float2(s1, c1);
            rp[4] = make_float2(s2, c2);
            rp[6] = make_float2(s3, c3);
        }
    }

    __syncthreads();
    // write this block's column partials: 1500 float2, coalesced
    float2* __restrict__ dst = ws + (b * BLKS + blk) * GN + h * HALF;
    for (int i = threadIdx.x; i < HALF; i += 256)
        dst[i] = make_float2(colsum[i * 2], colsum[i * 2 + 1]);
}

__global__ __launch_bounds__(256, 4) void geo_reduce_kernel(
    const float* __restrict__ p0,
    const float* __restrict__ p1,
    const float2* __restrict__ ws,
    float2* __restrict__ out)
{
    const int idx = blockIdx.x * 256 + threadIdx.x;
    if (idx < GB * GN) {
        // side1 output m: reduce 188 block partials for column m
        const int b = idx / GN;
        const int m = idx - b * GN;
        const float2* part = ws + b * BLKS * GN + m;
        float s = 0.f, c = 0.f;
        #pragma unroll 4
        for (int k = 0; k < BLKS; ++k) {
            float2 v = part[k * GN];
            s += v.x; c += v.y;
        }
        const float2 p = ((const float2*)p1)[idx];
        out[GB * GN + idx] = make_float2(p.x * s, p.y * c);
    } else if (idx < 2 * GB * GN) {
        // side0 output n: combine the two column-half row sums
        const int r = idx - GB * GN;
        const float2* rp = ws + COLPART_F2 + (r << 1);
        const float2 a = rp[0], d = rp[1];
        const float2 p = ((const float2*)p0)[r];
        out[r] = make_float2(p.x * (a.x + d.x), p.y * (a.y + d.y));
    }
}

extern "C" void kernel_launch(void* const* d_in, const int* in_sizes, int n_in,
                              void* d_out, int out_size, void* d_ws, size_t ws_size,
                              hipStream_t stream) {
    const float* points0 = (const float*)d_in[0];
    const float* points1 = (const float*)d_in[1];

    // ws usage: (4*188*3000 + 24000) float2 ~= 18.3 MB
    geo_pair_kernel<<<dim3(GB * BLKS * 2), dim3(256), 0, stream>>>(
        points0, points1, (float2*)d_ws);
    geo_reduce_kernel<<<dim3((2 * GB * GN + 255) / 256), dim3(256), 0, stream>>>(
        points0, points1, (const float2*)d_ws, (float2*)d_out);
}

// Round 3
// 93.589 us; speedup vs baseline: 1.8564x; 1.8564x over previous
//
#include <hip/hip_runtime.h>
#include <math.h>

// GeometricEmbedding: B=4, N=M=3000, d_model=2, sigma_d=1.0
// out[0..12000)  float2 = p0[b,n] * (sum_m sin d, sum_m cos d)
// out[12000..24000)     = p1[b,m] * (sum_n sin d, sum_n cos d)
// d = sqrt(max(2 - 2*<p0,p1>, 0)); sin/cos via HW trans ops in revolutions
// (1/2pi folded into the sqrt argument: r = sqrt(max(C2 - 2*K2*<p0,p1>, 0))).
//
// R9 == R8 resubmit (R8 bench was an infra failure: "container failed twice",
// no counters). Structure: each (b,n,m) pair evaluated ONCE; row sums in
// registers (4 independent rows/wave for trans-pipe ILP), column sums via
// wave-private LDS slices (plain ds_write_b64, NO atomics - R7's generic-ptr
// atomicAdd stalled waves 88%), merged by a 4-way block reduce + coalesced
// flush in 2 phases of 12 column-slots (LDS 24KB -> 6 blocks/CU). 2-deep q
// prefetch covers ~200cyc L2-hit latency.
// Trans floor: 36e6 evals * 3 ops / 64 lanes * 16cyc / 1024 SIMD ~= 11us.

#define GB 4
#define GN 3000
#define RB 16                       // rows per block (4 waves x 4 rows)
#define BLKS 188                    // ceil(3000/16); last block: 2 active waves
#define HALF 1500                   // columns per block (2 halves per batch)
#define K2 0.025330295910584444f    // (1/2pi)^2
#define C2 0.050660591821168888f    // 2*(1/2pi)^2

// ws layout (float2 units):
//   [0, COLPART_F2): colpart[(b*BLKS+blk)*GN + m] = block's 16-row sums at col m
//   [COLPART_F2, +24000): rowpart[(b*GN+n)*2 + h] = row n's half-h sums
#define COLPART_F2 (GB*BLKS*GN)

__device__ __forceinline__ float sreg(float x) {   // pin wave-uniform to SGPR
    return __int_as_float(__builtin_amdgcn_readfirstlane(__float_as_int(x)));
}

__global__ __launch_bounds__(256, 6) void geo_pair_kernel(
    const float* __restrict__ p0,
    const float* __restrict__ p1,
    float2* __restrict__ ws)
{
    __shared__ float2 cp[4][768];               // 24 KB, wave-private slices

    const int lane = threadIdx.x & 63;
    const int wv   = threadIdx.x >> 6;          // 0..3
    const int h    = blockIdx.x & 1;            // column half
    const int t    = blockIdx.x >> 1;           // 0..751
    const int b    = t / BLKS;                  // magic-mul
    const int blk  = t - b * BLKS;
    const int row0 = blk * RB + wv * 4;
    const bool active = (row0 < GN);            // tail block: waves 2,3 idle

    float s0=0.f,c0=0.f,s1=0.f,c1=0.f,s2=0.f,c2=0.f,s3=0.f,c3=0.f;
    float ax0=0.f,ay0=0.f,ax1=0.f,ay1=0.f,ax2=0.f,ay2=0.f,ax3=0.f,ay3=0.f;
    float2 pr0=make_float2(0.f,0.f), pr1=pr0, pr2=pr0, pr3=pr0;
    const float2* __restrict__ qp = (const float2*)p1;
    float2 qA = make_float2(0.f,0.f), qB = qA;
    const float c2v = C2;

    if (active) {
        const float2* ownp = (const float2*)p0 + b * GN + row0;
        pr0 = ownp[0]; pr1 = ownp[1]; pr2 = ownp[2]; pr3 = ownp[3];
        const float mm = -2.0f * K2;
        ax0 = sreg(mm * pr0.x); ay0 = sreg(mm * pr0.y);
        ax1 = sreg(mm * pr1.x); ay1 = sreg(mm * pr1.y);
        ax2 = sreg(mm * pr2.x); ay2 = sreg(mm * pr2.y);
        ax3 = sreg(mm * pr3.x); ay3 = sreg(mm * pr3.y);
        qp = (const float2*)p1 + b * GN + h * HALF + lane;
        qA = qp[0];                             // slot 0
        qB = qp[64];                            // slot 1
    } else {
        for (int i = lane; i < 768; i += 64)    // idle waves contribute zeros
            cp[wv][i] = make_float2(0.f, 0.f);
    }

    float2* cw = &cp[wv][lane];

#define STEP(q) do {                                                         \
    float t0 = fmaf(ax0, (q).x, fmaf(ay0, (q).y, c2v));                      \
    float t1 = fmaf(ax1, (q).x, fmaf(ay1, (q).y, c2v));                      \
    float t2 = fmaf(ax2, (q).x, fmaf(ay2, (q).y, c2v));                      \
    float t3 = fmaf(ax3, (q).x, fmaf(ay3, (q).y, c2v));                      \
    t0 = fmaxf(t0, 0.f); t1 = fmaxf(t1, 0.f);                                \
    t2 = fmaxf(t2, 0.f); t3 = fmaxf(t3, 0.f);                                \
    float r0 = __builtin_amdgcn_sqrtf(t0);                                   \
    float r1 = __builtin_amdgcn_sqrtf(t1);                                   \
    float r2 = __builtin_amdgcn_sqrtf(t2);                                   \
    float r3 = __builtin_amdgcn_sqrtf(t3);                                   \
    float sn0 = __builtin_amdgcn_sinf(r0), cs0 = __builtin_amdgcn_cosf(r0);  \
    float sn1 = __builtin_amdgcn_sinf(r1), cs1 = __builtin_amdgcn_cosf(r1);  \
    float sn2 = __builtin_amdgcn_sinf(r2), cs2 = __builtin_amdgcn_cosf(r2);  \
    float sn3 = __builtin_amdgcn_sinf(r3), cs3 = __builtin_amdgcn_cosf(r3);  \
    s0 += sn0; c0 += cs0; s1 += sn1; c1 += cs1;                              \
    s2 += sn2; c2 += cs2; s3 += sn3; c3 += cs3;                              \
    cw[0] = make_float2((sn0 + sn1) + (sn2 + sn3),                           \
                        (cs0 + cs1) + (cs2 + cs3));                          \
    cw += 64;                                                                \
} while (0)

    // ---- phase 0: slots 0..11 (cols h*1500 + 0..767) ----
    if (active) {
        #pragma unroll 1
        for (int js = 0; js < 10; ++js) {       // slots 0..9
            float2 qC = qp[128];                // prefetch slot js+2
            qp += 64;
            STEP(qA);
            qA = qB; qB = qC;
        }
        STEP(qA);                               // slot 10
        STEP(qB);                               // slot 11
        qA = qp[128];                           // slot 12 (qp at slot 10)
        qB = qp[192];                           // slot 13
        qp += 128;                              // qp -> slot 12
    }
    __syncthreads();
    float2* __restrict__ dst = ws + (b * BLKS + blk) * GN + h * HALF;
    for (int i = threadIdx.x; i < 768; i += 256) {
        float2 a0 = cp[0][i], a1 = cp[1][i], a2 = cp[2][i], a3 = cp[3][i];
        dst[i] = make_float2((a0.x + a1.x) + (a2.x + a3.x),
                             (a0.y + a1.y) + (a2.y + a3.y));
    }
    __syncthreads();

    // ---- phase 1: slots 12..22 full + slot 23 tail (cols 768..1499) ----
    cw = &cp[wv][lane];
    if (active) {
        #pragma unroll 1
        for (int js = 0; js < 9; ++js) {        // slots 12..20
            float2 qC = qp[128];                // prefetch up to slot 22
            qp += 64;
            STEP(qA);
            qA = qB; qB = qC;
        }
        STEP(qA);                               // slot 21
        STEP(qB);                               // slot 22
        if (lane < 28) {                        // slot 23: cols 1472..1499
            float2 qT = qp[128];                // qp at slot 21 -> slot 23
            STEP(qT);
        }
    }
    __syncthreads();
    for (int i = threadIdx.x; i < 732; i += 256) {
        float2 a0 = cp[0][i], a1 = cp[1][i], a2 = cp[2][i], a3 = cp[3][i];
        dst[768 + i] = make_float2((a0.x + a1.x) + (a2.x + a3.x),
                                   (a0.y + a1.y) + (a2.y + a3.y));
    }
#undef STEP

    // ---- row sums: wave shuffle reduce, lane0 writes half-partials ----
    if (active) {
        #pragma unroll
        for (int off = 32; off >= 1; off >>= 1) {
            s0 += __shfl_down(s0, off, 64);  c0 += __shfl_down(c0, off, 64);
            s1 += __shfl_down(s1, off, 64);  c1 += __shfl_down(c1, off, 64);
            s2 += __shfl_down(s2, off, 64);  c2 += __shfl_down(c2, off, 64);
            s3 += __shfl_down(s3, off, 64);  c3 += __shfl_down(c3, off, 64);
        }
        if (lane == 0) {
            float2* rp = ws + COLPART_F2 + ((b * GN + row0) << 1) + h;
            rp[0] = make_float2(s0, c0);
            rp[2] = make_float2(s1, c1);
            rp[4] = make_float2(s2, c2);
            rp[6] = make_float2(s3, c3);
        }
    }
}

__global__ __launch_bounds__(256, 4) void geo_reduce_kernel(
    const float* __restrict__ p0,
    const float* __restrict__ p1,
    const float2* __restrict__ ws,
    float2* __restrict__ out)
{
    const int idx = blockIdx.x * 256 + threadIdx.x;
    if (idx < GB * GN) {
        // side1 output m: reduce 188 block partials for column m
        const int b = idx / GN;
        const int m = idx - b * GN;
        const float2* part = ws + b * BLKS * GN + m;
        float s = 0.f, c = 0.f;
        #pragma unroll 4
        for (int k = 0; k < BLKS; ++k) {
            float2 v = part[k * GN];
            s += v.x; c += v.y;
        }
        const float2 p = ((const float2*)p1)[idx];
        out[GB * GN + idx] = make_float2(p.x * s, p.y * c);
    } else if (idx < 2 * GB * GN) {
        // side0 output n: combine the two column-half row sums
        const int r = idx - GB * GN;
        const float2* rp = ws + COLPART_F2 + (r << 1);
        const float2 a = rp[0], d = rp[1];
        const float2 p = ((const float2*)p0)[r];
        out[r] = make_float2(p.x * (a.x + d.x), p.y * (a.y + d.y));
    }
}

extern "C" void kernel_launch(void* const* d_in, const int* in_sizes, int n_in,
                              void* d_out, int out_size, void* d_ws, size_t ws_size,
                              hipStream_t stream) {
    const float* points0 = (const float*)d_in[0];
    const float* points1 = (const float*)d_in[1];

    // ws usage: (4*188*3000 + 24000) float2 ~= 18.3 MB
    geo_pair_kernel<<<dim3(GB * BLKS * 2), dim3(256), 0, stream>>>(
        points0, points1, (float2*)d_ws);
    geo_reduce_kernel<<<dim3((2 * GB * GN + 255) / 256), dim3(256), 0, stream>>>(
        points0, points1, (const float2*)d_ws, (float2*)d_out);
}

// Round 4
// 85.845 us; speedup vs baseline: 2.0239x; 1.0902x over previous
//
#include <hip/hip_runtime.h>
#include <math.h>

// GeometricEmbedding: B=4, N=M=3000, d_model=2, sigma_d=1.0
// out[0..12000)  float2 = p0[b,n] * (sum_m sin d, sum_m cos d)
// out[12000..24000)     = p1[b,m] * (sum_n sin d, sum_n cos d)
// d = sqrt(max(2 - 2*<p0,p1>, 0)); sin/cos via HW trans ops in revolutions
// (1/2pi folded into the sqrt argument: r = sqrt(max(C2 - 2*K2*<p0,p1>, 0))).
//
// R10: R9 passed; budget decomposition (93.6 = 44 fill + ~50 pair+reduce)
// shows the REDUCE kernel (~25-30us) now rivals the pair kernel. Cause:
// side-1 reduce was 12000 threads (<1 wave/CU) each with a 188-deep serial
// load chain -> latency-bound, 10x over its 2.9us BW floor. This round:
// reduce parallelized over k (256thr block = 32 cols x 8 k-chunks of 24,
// independent unrolled loads, LDS merge). Pair kernel byte-identical to R9
// (each (b,n,m) evaluated ONCE; wave-private LDS column slices, no atomics;
// 2-phase flush; 2-deep q prefetch). Trans floor of pair: ~11us.

#define GB 4
#define GN 3000
#define RB 16                       // rows per block (4 waves x 4 rows)
#define BLKS 188                    // ceil(3000/16); last block: 2 active waves
#define HALF 1500                   // columns per block (2 halves per batch)
#define K2 0.025330295910584444f    // (1/2pi)^2
#define C2 0.050660591821168888f    // 2*(1/2pi)^2

// ws layout (float2 units):
//   [0, COLPART_F2): colpart[(b*BLKS+blk)*GN + m] = block's 16-row sums at col m
//   [COLPART_F2, +24000): rowpart[(b*GN+n)*2 + h] = row n's half-h sums
#define COLPART_F2 (GB*BLKS*GN)

__device__ __forceinline__ float sreg(float x) {   // pin wave-uniform to SGPR
    return __int_as_float(__builtin_amdgcn_readfirstlane(__float_as_int(x)));
}

__global__ __launch_bounds__(256, 6) void geo_pair_kernel(
    const float* __restrict__ p0,
    const float* __restrict__ p1,
    float2* __restrict__ ws)
{
    __shared__ float2 cp[4][768];               // 24 KB, wave-private slices

    const int lane = threadIdx.x & 63;
    const int wv   = threadIdx.x >> 6;          // 0..3
    const int h    = blockIdx.x & 1;            // column half
    const int t    = blockIdx.x >> 1;           // 0..751
    const int b    = t / BLKS;                  // magic-mul
    const int blk  = t - b * BLKS;
    const int row0 = blk * RB + wv * 4;
    const bool active = (row0 < GN);            // tail block: waves 2,3 idle

    float s0=0.f,c0=0.f,s1=0.f,c1=0.f,s2=0.f,c2=0.f,s3=0.f,c3=0.f;
    float ax0=0.f,ay0=0.f,ax1=0.f,ay1=0.f,ax2=0.f,ay2=0.f,ax3=0.f,ay3=0.f;
    float2 pr0=make_float2(0.f,0.f), pr1=pr0, pr2=pr0, pr3=pr0;
    const float2* __restrict__ qp = (const float2*)p1;
    float2 qA = make_float2(0.f,0.f), qB = qA;
    const float c2v = C2;

    if (active) {
        const float2* ownp = (const float2*)p0 + b * GN + row0;
        pr0 = ownp[0]; pr1 = ownp[1]; pr2 = ownp[2]; pr3 = ownp[3];
        const float mm = -2.0f * K2;
        ax0 = sreg(mm * pr0.x); ay0 = sreg(mm * pr0.y);
        ax1 = sreg(mm * pr1.x); ay1 = sreg(mm * pr1.y);
        ax2 = sreg(mm * pr2.x); ay2 = sreg(mm * pr2.y);
        ax3 = sreg(mm * pr3.x); ay3 = sreg(mm * pr3.y);
        qp = (const float2*)p1 + b * GN + h * HALF + lane;
        qA = qp[0];                             // slot 0
        qB = qp[64];                            // slot 1
    } else {
        for (int i = lane; i < 768; i += 64)    // idle waves contribute zeros
            cp[wv][i] = make_float2(0.f, 0.f);
    }

    float2* cw = &cp[wv][lane];

#define STEP(q) do {                                                         \
    float t0 = fmaf(ax0, (q).x, fmaf(ay0, (q).y, c2v));                      \
    float t1 = fmaf(ax1, (q).x, fmaf(ay1, (q).y, c2v));                      \
    float t2 = fmaf(ax2, (q).x, fmaf(ay2, (q).y, c2v));                      \
    float t3 = fmaf(ax3, (q).x, fmaf(ay3, (q).y, c2v));                      \
    t0 = fmaxf(t0, 0.f); t1 = fmaxf(t1, 0.f);                                \
    t2 = fmaxf(t2, 0.f); t3 = fmaxf(t3, 0.f);                                \
    float r0 = __builtin_amdgcn_sqrtf(t0);                                   \
    float r1 = __builtin_amdgcn_sqrtf(t1);                                   \
    float r2 = __builtin_amdgcn_sqrtf(t2);                                   \
    float r3 = __builtin_amdgcn_sqrtf(t3);                                   \
    float sn0 = __builtin_amdgcn_sinf(r0), cs0 = __builtin_amdgcn_cosf(r0);  \
    float sn1 = __builtin_amdgcn_sinf(r1), cs1 = __builtin_amdgcn_cosf(r1);  \
    float sn2 = __builtin_amdgcn_sinf(r2), cs2 = __builtin_amdgcn_cosf(r2);  \
    float sn3 = __builtin_amdgcn_sinf(r3), cs3 = __builtin_amdgcn_cosf(r3);  \
    s0 += sn0; c0 += cs0; s1 += sn1; c1 += cs1;                              \
    s2 += sn2; c2 += cs2; s3 += sn3; c3 += cs3;                              \
    cw[0] = make_float2((sn0 + sn1) + (sn2 + sn3),                           \
                        (cs0 + cs1) + (cs2 + cs3));                          \
    cw += 64;                                                                \
} while (0)

    // ---- phase 0: slots 0..11 (cols h*1500 + 0..767) ----
    if (active) {
        #pragma unroll 1
        for (int js = 0; js < 10; ++js) {       // slots 0..9
            float2 qC = qp[128];                // prefetch slot js+2
            qp += 64;
            STEP(qA);
            qA = qB; qB = qC;
        }
        STEP(qA);                               // slot 10
        STEP(qB);                               // slot 11
        qA = qp[128];                           // slot 12 (qp at slot 10)
        qB = qp[192];                           // slot 13
        qp += 128;                              // qp -> slot 12
    }
    __syncthreads();
    float2* __restrict__ dst = ws + (b * BLKS + blk) * GN + h * HALF;
    for (int i = threadIdx.x; i < 768; i += 256) {
        float2 a0 = cp[0][i], a1 = cp[1][i], a2 = cp[2][i], a3 = cp[3][i];
        dst[i] = make_float2((a0.x + a1.x) + (a2.x + a3.x),
                             (a0.y + a1.y) + (a2.y + a3.y));
    }
    __syncthreads();

    // ---- phase 1: slots 12..22 full + slot 23 tail (cols 768..1499) ----
    cw = &cp[wv][lane];
    if (active) {
        #pragma unroll 1
        for (int js = 0; js < 9; ++js) {        // slots 12..20
            float2 qC = qp[128];                // prefetch up to slot 22
            qp += 64;
            STEP(qA);
            qA = qB; qB = qC;
        }
        STEP(qA);                               // slot 21
        STEP(qB);                               // slot 22
        if (lane < 28) {                        // slot 23: cols 1472..1499
            float2 qT = qp[128];                // qp at slot 21 -> slot 23
            STEP(qT);
        }
    }
    __syncthreads();
    for (int i = threadIdx.x; i < 732; i += 256) {
        float2 a0 = cp[0][i], a1 = cp[1][i], a2 = cp[2][i], a3 = cp[3][i];
        dst[768 + i] = make_float2((a0.x + a1.x) + (a2.x + a3.x),
                                   (a0.y + a1.y) + (a2.y + a3.y));
    }
#undef STEP

    // ---- row sums: wave shuffle reduce, lane0 writes half-partials ----
    if (active) {
        #pragma unroll
        for (int off = 32; off >= 1; off >>= 1) {
            s0 += __shfl_down(s0, off, 64);  c0 += __shfl_down(c0, off, 64);
            s1 += __shfl_down(s1, off, 64);  c1 += __shfl_down(c1, off, 64);
            s2 += __shfl_down(s2, off, 64);  c2 += __shfl_down(c2, off, 64);
            s3 += __shfl_down(s3, off, 64);  c3 += __shfl_down(c3, off, 64);
        }
        if (lane == 0) {
            float2* rp = ws + COLPART_F2 + ((b * GN + row0) << 1) + h;
            rp[0] = make_float2(s0, c0);
            rp[2] = make_float2(s1, c1);
            rp[4] = make_float2(s2, c2);
            rp[6] = make_float2(s3, c3);
        }
    }
}

// R10 reduce: side1 = 375 blocks of (32 cols x 8 k-chunks); each thread sums
// 24 independent strided loads (unrolled -> all in flight), LDS 8-way merge.
// side0 = 47 blocks of plain 2-read combine. 422 blocks total.
__global__ __launch_bounds__(256, 4) void geo_reduce_kernel(
    const float* __restrict__ p0,
    const float* __restrict__ p1,
    const float2* __restrict__ ws,
    float2* __restrict__ out)
{
    __shared__ float2 acc[8][32];
    const int blk = blockIdx.x;
    if (blk < 375) {
        const int c  = threadIdx.x & 31;        // column within group
        const int kc = threadIdx.x >> 5;        // k-chunk 0..7
        const int g  = blk * 32 + c;            // flat (b,m): 0..11999
        const int b  = g / GN;                  // magic-mul
        const int m  = g - b * GN;
        const float2* __restrict__ base = ws + b * (BLKS * GN) + m;
        const int k0 = kc * 24;
        float s = 0.f, cc = 0.f;
        #pragma unroll
        for (int j = 0; j < 24; ++j) {          // kc==7: 20 live (k<188 guard)
            const int k = k0 + j;
            if (k < BLKS) {
                float2 v = base[k * GN];
                s += v.x; cc += v.y;
            }
        }
        acc[kc][c] = make_float2(s, cc);
        __syncthreads();
        if (kc == 0) {
            float2 r = acc[0][c];
            #pragma unroll
            for (int j = 1; j < 8; ++j) { r.x += acc[j][c].x; r.y += acc[j][c].y; }
            const float2 p = ((const float2*)p1)[g];
            out[GB * GN + g] = make_float2(p.x * r.x, p.y * r.y);
        }
    } else {
        const int r = (blk - 375) * 256 + threadIdx.x;
        if (r < GB * GN) {
            const float2* rp = ws + COLPART_F2 + (r << 1);
            const float2 a = rp[0], d = rp[1];
            const float2 p = ((const float2*)p0)[r];
            out[r] = make_float2(p.x * (a.x + d.x), p.y * (a.y + d.y));
        }
    }
}

extern "C" void kernel_launch(void* const* d_in, const int* in_sizes, int n_in,
                              void* d_out, int out_size, void* d_ws, size_t ws_size,
                              hipStream_t stream) {
    const float* points0 = (const float*)d_in[0];
    const float* points1 = (const float*)d_in[1];

    // ws usage: (4*188*3000 + 24000) float2 ~= 18.3 MB
    geo_pair_kernel<<<dim3(GB * BLKS * 2), dim3(256), 0, stream>>>(
        points0, points1, (float2*)d_ws);
    geo_reduce_kernel<<<dim3(375 + 47), dim3(256), 0, stream>>>(
        points0, points1, (const float2*)d_ws, (float2*)d_out);
}

// Round 5
// 80.506 us; speedup vs baseline: 2.1581x; 1.0663x over previous
//
#include <hip/hip_runtime.h>
#include <math.h>

// GeometricEmbedding: B=4, N=M=3000, d_model=2, sigma_d=1.0
// out[0..12000)  float2 = p0[b,n] * (sum_m sin d, sum_m cos d)
// out[12000..24000)     = p1[b,m] * (sum_n sin d, sum_n cos d)
// d = sqrt(max(2 - 2*<p0,p1>, 0)); sin/cos via HW trans ops in revolutions
// (1/2pi folded into the sqrt argument: r = sqrt(max(C2 - 2*K2*<p0,p1>, 0))).
//
// R11: R10 budget (85.8 = 44 fill + ~5 reduce + ~37 pair) shows the pair
// kernel equals R0's DOUBLE-work kernel: per-step machinery (ds_write, col
// merge, flush barriers) eats the halved-trans win. This round: 8 rows/wave
// (was 4). Same 36e6 evals & ~11us trans floor, but HALF the wave-steps ->
// half the loop/prefetch/ds_write overhead, half the flush blocks (col
// partial traffic 18->9MB), half the reduce depth (188->94). 8 independent
// trans chains/step keep the pipe fed at ~3 blocks/CU.

#define GB 4
#define GN 3000
#define RB 32                       // rows per block (4 waves x 8 rows)
#define BLKS 94                     // 3000/32 rounded up; blk93 wave3 inactive
#define HALF 1500                   // columns per block (2 halves per batch)
#define K2 0.025330295910584444f    // (1/2pi)^2
#define C2 0.050660591821168888f    // 2*(1/2pi)^2

// ws layout (float2 units):
//   [0, COLPART_F2): colpart[(b*BLKS+blk)*GN + m] = block's 32-row sums at col m
//   [COLPART_F2, +24000): rowpart[(b*GN+n)*2 + h] = row n's half-h sums
#define COLPART_F2 (GB*BLKS*GN)

__device__ __forceinline__ float sreg(float x) {   // pin wave-uniform to SGPR
    return __int_as_float(__builtin_amdgcn_readfirstlane(__float_as_int(x)));
}

__global__ __launch_bounds__(256, 4) void geo_pair_kernel(
    const float* __restrict__ p0,
    const float* __restrict__ p1,
    float2* __restrict__ ws)
{
    __shared__ float2 cp[4][768];               // 24 KB, wave-private slices

    const int lane = threadIdx.x & 63;
    const int wv   = threadIdx.x >> 6;          // 0..3
    const int h    = blockIdx.x & 1;            // column half
    const int t    = blockIdx.x >> 1;           // 0..375
    const int b    = t / BLKS;                  // magic-mul
    const int blk  = t - b * BLKS;
    const int row0 = blk * RB + wv * 8;
    const bool active = (row0 < GN);            // blk93 wave3: rows 3000+ -> idle

    float s[8], c[8], ax[8], ay[8];
    float2 pr[8];
    #pragma unroll
    for (int r = 0; r < 8; ++r) {
        s[r] = 0.f; c[r] = 0.f; ax[r] = 0.f; ay[r] = 0.f;
        pr[r] = make_float2(0.f, 0.f);
    }
    const float2* __restrict__ qp = (const float2*)p1;
    float2 qA = make_float2(0.f, 0.f), qB = qA;
    const float c2v = C2;

    if (active) {
        const float2* ownp = (const float2*)p0 + b * GN + row0;
        const float mm = -2.0f * K2;
        #pragma unroll
        for (int r = 0; r < 8; ++r) {
            pr[r] = ownp[r];
            ax[r] = sreg(mm * pr[r].x);
            ay[r] = sreg(mm * pr[r].y);
        }
        qp = (const float2*)p1 + b * GN + h * HALF + lane;
        qA = qp[0];                             // slot 0
        qB = qp[64];                            // slot 1
    } else {
        for (int i = lane; i < 768; i += 64)    // idle wave contributes zeros
            cp[wv][i] = make_float2(0.f, 0.f);
    }

    float2* cw = &cp[wv][lane];

#define STEP(q) do {                                                         \
    float sn[8], cs[8];                                                      \
    _Pragma("unroll")                                                        \
    for (int r = 0; r < 8; ++r) {                                            \
        float tt = fmaf(ax[r], (q).x, fmaf(ay[r], (q).y, c2v));              \
        tt = fmaxf(tt, 0.f);                                                 \
        float rr = __builtin_amdgcn_sqrtf(tt);                               \
        sn[r] = __builtin_amdgcn_sinf(rr);                                   \
        cs[r] = __builtin_amdgcn_cosf(rr);                                   \
        s[r] += sn[r]; c[r] += cs[r];                                        \
    }                                                                        \
    float ssum = ((sn[0]+sn[1]) + (sn[2]+sn[3]))                             \
               + ((sn[4]+sn[5]) + (sn[6]+sn[7]));                            \
    float csum = ((cs[0]+cs[1]) + (cs[2]+cs[3]))                             \
               + ((cs[4]+cs[5]) + (cs[6]+cs[7]));                            \
    cw[0] = make_float2(ssum, csum);                                         \
    cw += 64;                                                                \
} while (0)

    // ---- phase 0: slots 0..11 (cols h*1500 + 0..767) ----
    if (active) {
        #pragma unroll 1
        for (int js = 0; js < 10; ++js) {       // slots 0..9
            float2 qC = qp[128];                // prefetch slot js+2
            qp += 64;
            STEP(qA);
            qA = qB; qB = qC;
        }
        STEP(qA);                               // slot 10
        STEP(qB);                               // slot 11
        qA = qp[128];                           // slot 12 (qp at slot 10)
        qB = qp[192];                           // slot 13
        qp += 128;                              // qp -> slot 12
    }
    __syncthreads();
    float2* __restrict__ dst = ws + (b * BLKS + blk) * GN + h * HALF;
    for (int i = threadIdx.x; i < 768; i += 256) {
        float2 a0 = cp[0][i], a1 = cp[1][i], a2 = cp[2][i], a3 = cp[3][i];
        dst[i] = make_float2((a0.x + a1.x) + (a2.x + a3.x),
                             (a0.y + a1.y) + (a2.y + a3.y));
    }
    __syncthreads();

    // ---- phase 1: slots 12..22 full + slot 23 tail (cols 768..1499) ----
    cw = &cp[wv][lane];
    if (active) {
        #pragma unroll 1
        for (int js = 0; js < 9; ++js) {        // slots 12..20
            float2 qC = qp[128];                // prefetch up to slot 22
            qp += 64;
            STEP(qA);
            qA = qB; qB = qC;
        }
        STEP(qA);                               // slot 21
        STEP(qB);                               // slot 22
        if (lane < 28) {                        // slot 23: cols 1472..1499
            float2 qT = qp[128];                // qp at slot 21 -> slot 23
            STEP(qT);
        }
    }
    __syncthreads();
    for (int i = threadIdx.x; i < 732; i += 256) {
        float2 a0 = cp[0][i], a1 = cp[1][i], a2 = cp[2][i], a3 = cp[3][i];
        dst[768 + i] = make_float2((a0.x + a1.x) + (a2.x + a3.x),
                                   (a0.y + a1.y) + (a2.y + a3.y));
    }
#undef STEP

    // ---- row sums: wave shuffle reduce, lane0 writes half-partials ----
    if (active) {
        #pragma unroll
        for (int off = 32; off >= 1; off >>= 1) {
            #pragma unroll
            for (int r = 0; r < 8; ++r) {
                s[r] += __shfl_down(s[r], off, 64);
                c[r] += __shfl_down(c[r], off, 64);
            }
        }
        if (lane == 0) {
            float2* rp = ws + COLPART_F2 + ((b * GN + row0) << 1) + h;
            #pragma unroll
            for (int r = 0; r < 8; ++r)
                rp[r * 2] = make_float2(s[r], c[r]);
        }
    }
}

// Reduce: side1 = 375 blocks of (32 cols x 8 k-chunks of 12); each thread
// sums 12 independent strided loads, LDS 8-way merge. side0 = 47 blocks.
__global__ __launch_bounds__(256, 4) void geo_reduce_kernel(
    const float* __restrict__ p0,
    const float* __restrict__ p1,
    const float2* __restrict__ ws,
    float2* __restrict__ out)
{
    __shared__ float2 acc[8][32];
    const int blk = blockIdx.x;
    if (blk < 375) {
        const int cc = threadIdx.x & 31;        // column within group
        const int kc = threadIdx.x >> 5;        // k-chunk 0..7
        const int g  = blk * 32 + cc;           // flat (b,m): 0..11999
        const int b  = g / GN;                  // magic-mul
        const int m  = g - b * GN;
        const float2* __restrict__ base = ws + b * (BLKS * GN) + m;
        const int k0 = kc * 12;
        float sv = 0.f, cv = 0.f;
        #pragma unroll
        for (int j = 0; j < 12; ++j) {          // kc==7: 10 live (k<94 guard)
            const int k = k0 + j;
            if (k < BLKS) {
                float2 v = base[k * GN];
                sv += v.x; cv += v.y;
            }
        }
        acc[kc][cc] = make_float2(sv, cv);
        __syncthreads();
        if (kc == 0) {
            float2 r = acc[0][cc];
            #pragma unroll
            for (int j = 1; j < 8; ++j) { r.x += acc[j][cc].x; r.y += acc[j][cc].y; }
            const float2 p = ((const float2*)p1)[g];
            out[GB * GN + g] = make_float2(p.x * r.x, p.y * r.y);
        }
    } else {
        const int r = (blk - 375) * 256 + threadIdx.x;
        if (r < GB * GN) {
            const float2* rp = ws + COLPART_F2 + (r << 1);
            const float2 a = rp[0], d = rp[1];
            const float2 p = ((const float2*)p0)[r];
            out[r] = make_float2(p.x * (a.x + d.x), p.y * (a.y + d.y));
        }
    }
}

extern "C" void kernel_launch(void* const* d_in, const int* in_sizes, int n_in,
                              void* d_out, int out_size, void* d_ws, size_t ws_size,
                              hipStream_t stream) {
    const float* points0 = (const float*)d_in[0];
    const float* points1 = (const float*)d_in[1];

    // ws usage: (4*94*3000 + 24000) float2 ~= 9.2 MB
    geo_pair_kernel<<<dim3(GB * BLKS * 2), dim3(256), 0, stream>>>(
        points0, points1, (float2*)d_ws);
    geo_reduce_kernel<<<dim3(375 + 47), dim3(256), 0, stream>>>(
        points0, points1, (const float2*)d_ws, (float2*)d_out);
}